// Round 7
// baseline (275.116 us; speedup 1.0000x reference)
//
#include <hip/hip_runtime.h>
#include <math.h>

// SubsetOperator (Gumbel top-K relaxation), B=4096 rows, N=8192 cols, K=8, TAU=1.
// Exp-domain transform: w = exp(s+g-M0); per iter: oh = w/sum; kh += oh;
// w = fma(-oh, w, w). One exp per element; K-loop is pure mul/fma + sum-reduce.
//
// Geometry fixed by R4/R5/R6 sweep: 256 thr x 32 elems is the VALU-minimal
// shape (reduce amortized over most elements); occupancy is NOT the limiter
// (R6: 75% occ, slower). Round-7 cuts VALU issue count:
//  - f32x2 packed math in K-loop (v_pk_{mul,add,fma}_f32) — same VGPR state
//  - __builtin_amdgcn_rcpf for the per-iter normalizer (vs ~10-instr IEEE div)
//  - __launch_bounds__(256,8) to permit 8 blocks/CU

#define BROWS 4096
#define NCOLS 8192
#define KITER 8
#define THREADS 256
#define VECS 8                    // 8 x float4 = 32 elems/thread
#define NWAVES (THREADS / 64)     // 4
#define M0 24.0f

typedef float f32x4 __attribute__((ext_vector_type(4)));
typedef float f32x2 __attribute__((ext_vector_type(2)));

__global__ __launch_bounds__(THREADS, 8)
void subset_op_kernel(const float* __restrict__ scores,
                      const float* __restrict__ g,
                      float* __restrict__ out) {
  const int tid = threadIdx.x;
  const int lane = tid & 63;
  const int wave = tid >> 6;
  const long long rbase = (long long)blockIdx.x * NCOLS;

  f32x2 w2[2 * VECS], kh2[2 * VECS];

  // ---- load, w = exp(s + g - M0); first partial sum ----
  float sum = 0.0f;
#pragma unroll
  for (int j = 0; j < VECS; ++j) {
    const int off = j * 1024 + tid * 4;
    const f32x4 sv = *(const f32x4*)(scores + rbase + off);
    const f32x4 gv = *(const f32x4*)(g + rbase + off);
    f32x2 lo, hi;
    lo.x = __expf(sv.x + gv.x - M0);
    lo.y = __expf(sv.y + gv.y - M0);
    hi.x = __expf(sv.z + gv.z - M0);
    hi.y = __expf(sv.w + gv.w - M0);
    w2[2 * j] = lo; w2[2 * j + 1] = hi;
    kh2[2 * j] = (f32x2){0.0f, 0.0f};
    kh2[2 * j + 1] = (f32x2){0.0f, 0.0f};
    sum += (lo.x + lo.y) + (hi.x + hi.y);
  }

  __shared__ float red[2][NWAVES];

  // ---- K iterations: block sum-reduce, packed multiplicative mask update ----
#pragma unroll 1
  for (int k = 0; k < KITER; ++k) {
    float ps = sum;
#pragma unroll
    for (int off = 32; off > 0; off >>= 1) ps += __shfl_xor(ps, off);
    if (lane == 0) red[k & 1][wave] = ps;
    __syncthreads();
    const f32x4 rv = *(const f32x4*)red[k & 1];
    const float tot = (rv.x + rv.y) + (rv.z + rv.w);
    const float inv = __builtin_amdgcn_rcpf(tot);   // ~1ulp, threshold is 6e-2
    const f32x2 iv = {inv, inv};

    f32x2 s0 = {0.0f, 0.0f}, s1 = {0.0f, 0.0f};
    f32x2 s2 = {0.0f, 0.0f}, s3 = {0.0f, 0.0f};
#pragma unroll
    for (int j = 0; j < 2 * VECS; ++j) {
      const f32x2 oh = w2[j] * iv;                       // v_pk_mul_f32
      kh2[j] += oh;                                      // v_pk_add_f32
      w2[j] = __builtin_elementwise_fma(-oh, w2[j], w2[j]);  // v_pk_fma_f32
      if ((j & 3) == 0)      s0 += w2[j];
      else if ((j & 3) == 1) s1 += w2[j];
      else if ((j & 3) == 2) s2 += w2[j];
      else                   s3 += w2[j];
    }
    const f32x2 sv2 = (s0 + s1) + (s2 + s3);
    sum = sv2.x + sv2.y;
  }

  // ---- store khot (nontemporal: written once, never re-read) ----
#pragma unroll
  for (int j = 0; j < VECS; ++j) {
    const int off = j * 1024 + tid * 4;
    f32x4 v;
    v.x = kh2[2 * j].x;     v.y = kh2[2 * j].y;
    v.z = kh2[2 * j + 1].x; v.w = kh2[2 * j + 1].y;
    __builtin_nontemporal_store(v, (f32x4*)(out + rbase + off));
  }
}

extern "C" void kernel_launch(void* const* d_in, const int* in_sizes, int n_in,
                              void* d_out, int out_size, void* d_ws, size_t ws_size,
                              hipStream_t stream) {
  const float* scores = (const float*)d_in[0];
  const float* g = (const float*)d_in[1];
  float* out = (float*)d_out;
  (void)in_sizes; (void)n_in; (void)out_size; (void)d_ws; (void)ws_size;

  subset_op_kernel<<<BROWS, THREADS, 0, stream>>>(scores, g, out);
}

// Round 8
// 69.175 us; speedup vs baseline: 3.9771x; 3.9771x over previous
//
#include <hip/hip_runtime.h>
#include <math.h>

// SubsetOperator (Gumbel top-K relaxation), B=4096 rows, N=8192 cols, K=8, TAU=1.
// Exp-domain transform: w = exp(s+g-M0); per iter: oh = w/sum; kh += oh;
// w = fma(-oh, w, w). One exp per element; K-loop is pure mul/fma + sum-reduce.
//
// R7 lesson: __launch_bounds__(256,8) capped VGPRs at 64 -> spilled the
// 32-float state to scratch (FETCH 131->424MB, 4x slowdown). Occupancy is NOT
// the limiter (R5: 29% occ ~ R4's 54% occ perf); registers are sacred.
// R8 = R7 minus the min-waves clause: packed f32x2 K-loop + rcp normalizer,
// natural register allocation.

#define BROWS 4096
#define NCOLS 8192
#define KITER 8
#define THREADS 256
#define VECS 8                    // 8 x float4 = 32 elems/thread
#define NWAVES (THREADS / 64)     // 4
#define M0 24.0f

typedef float f32x4 __attribute__((ext_vector_type(4)));
typedef float f32x2 __attribute__((ext_vector_type(2)));

__global__ __launch_bounds__(THREADS)
void subset_op_kernel(const float* __restrict__ scores,
                      const float* __restrict__ g,
                      float* __restrict__ out) {
  const int tid = threadIdx.x;
  const int lane = tid & 63;
  const int wave = tid >> 6;
  const long long rbase = (long long)blockIdx.x * NCOLS;

  f32x2 w2[2 * VECS], kh2[2 * VECS];

  // ---- load, w = exp(s + g - M0); first partial sum ----
  float sum = 0.0f;
#pragma unroll
  for (int j = 0; j < VECS; ++j) {
    const int off = j * 1024 + tid * 4;
    const f32x4 sv = *(const f32x4*)(scores + rbase + off);
    const f32x4 gv = *(const f32x4*)(g + rbase + off);
    f32x2 lo, hi;
    lo.x = __expf(sv.x + gv.x - M0);
    lo.y = __expf(sv.y + gv.y - M0);
    hi.x = __expf(sv.z + gv.z - M0);
    hi.y = __expf(sv.w + gv.w - M0);
    w2[2 * j] = lo; w2[2 * j + 1] = hi;
    kh2[2 * j] = (f32x2){0.0f, 0.0f};
    kh2[2 * j + 1] = (f32x2){0.0f, 0.0f};
    sum += (lo.x + lo.y) + (hi.x + hi.y);
  }

  __shared__ float red[2][NWAVES];

  // ---- K iterations: block sum-reduce, packed multiplicative mask update ----
#pragma unroll 1
  for (int k = 0; k < KITER; ++k) {
    float ps = sum;
#pragma unroll
    for (int off = 32; off > 0; off >>= 1) ps += __shfl_xor(ps, off);
    if (lane == 0) red[k & 1][wave] = ps;
    __syncthreads();
    const f32x4 rv = *(const f32x4*)red[k & 1];
    const float tot = (rv.x + rv.y) + (rv.z + rv.w);
    const float inv = __builtin_amdgcn_rcpf(tot);   // ~1ulp, threshold is 6e-2
    const f32x2 iv = {inv, inv};

    f32x2 s0 = {0.0f, 0.0f}, s1 = {0.0f, 0.0f};
    f32x2 s2 = {0.0f, 0.0f}, s3 = {0.0f, 0.0f};
#pragma unroll
    for (int j = 0; j < 2 * VECS; ++j) {
      const f32x2 oh = w2[j] * iv;                       // v_pk_mul_f32
      kh2[j] += oh;                                      // v_pk_add_f32
      w2[j] = __builtin_elementwise_fma(-oh, w2[j], w2[j]);  // v_pk_fma_f32
      if ((j & 3) == 0)      s0 += w2[j];
      else if ((j & 3) == 1) s1 += w2[j];
      else if ((j & 3) == 2) s2 += w2[j];
      else                   s3 += w2[j];
    }
    const f32x2 sv2 = (s0 + s1) + (s2 + s3);
    sum = sv2.x + sv2.y;
  }

  // ---- store khot (nontemporal: written once, never re-read) ----
#pragma unroll
  for (int j = 0; j < VECS; ++j) {
    const int off = j * 1024 + tid * 4;
    f32x4 v;
    v.x = kh2[2 * j].x;     v.y = kh2[2 * j].y;
    v.z = kh2[2 * j + 1].x; v.w = kh2[2 * j + 1].y;
    __builtin_nontemporal_store(v, (f32x4*)(out + rbase + off));
  }
}

extern "C" void kernel_launch(void* const* d_in, const int* in_sizes, int n_in,
                              void* d_out, int out_size, void* d_ws, size_t ws_size,
                              hipStream_t stream) {
  const float* scores = (const float*)d_in[0];
  const float* g = (const float*)d_in[1];
  float* out = (float*)d_out;
  (void)in_sizes; (void)n_in; (void)out_size; (void)d_ws; (void)ws_size;

  subset_op_kernel<<<BROWS, THREADS, 0, stream>>>(scores, g, out);
}